// Round 8
// baseline (891.303 us; speedup 1.0000x reference)
//
#include <hip/hip_runtime.h>

// CRF negative mean log-likelihood, B=64, T=512, U=256.
//
// Round 8 (= round-7 resubmit; infra failure, experiment never ran):
// DIAGNOSTIC ROUND. Production kernel = r4 verbatim (best: 224.8us).
// Plus 4 ablation kernels (write only to guarded ws scratch, never d_out):
//   abl1_nofeed : step reads a constant LDS buffer (no serial dep via LDS)
//   abl5_nobar  : step without s_barrier (races; timing only)
//   abl3_exch   : skeleton + 1-scalar LDS round-trip + barrier (no MFMA)
//   abl4_comp   : skeleton + reg-fed MFMA chain (no LDS, no barrier)
// Per-dispatch dur_us from rocprof gives 5 measurements in one round.

#define Bc 64
#define Tc 512
#define Uc 256
#define LOG2E 1.4426950408889634f
#define LN2   0.6931471805599453f
#define CC2   7.2134752f   // per-step normalizer in log2 domain (= 5.0 nats)

typedef __bf16 bf16x8 __attribute__((ext_vector_type(8)));
typedef float  f32x4  __attribute__((ext_vector_type(4)));

__device__ __forceinline__ void wg_barrier() {
    asm volatile("s_waitcnt lgkmcnt(0)" ::: "memory");
    __builtin_amdgcn_s_barrier();
    asm volatile("" ::: "memory");
}
__device__ __forceinline__ void lds_fence() {
    asm volatile("s_waitcnt lgkmcnt(0)" ::: "memory");
}

// ============================ PRODUCTION (r4 verbatim) ======================
__global__ __launch_bounds__(512)
void crf_fwd(const float* __restrict__ pot, const int* __restrict__ tags,
             const int* __restrict__ seqlen, const float* __restrict__ trans,
             float* __restrict__ ws, float* __restrict__ out)
{
    const int b    = blockIdx.x;
    const int tid  = threadIdx.x;
    const int lane = tid & 63;
    const int w    = tid >> 6;
    const int g4   = lane >> 4;
    const int c16  = lane & 15;
    const int L    = seqlen[b];

    __shared__ __align__(16) __bf16 ea_lds[2][Uc];
    __shared__ __align__(16) float mx[2][8];
    __shared__ float wred[8];
    __shared__ float redU[8], redB[8];

    const float* potb = pot  + (size_t)b * Tc * Uc;
    const int*   tagb = tags + b * Tc;

    bf16x8 bfr[8][2];
    #pragma unroll
    for (int kt = 0; kt < 8; ++kt) {
        #pragma unroll
        for (int nt = 0; nt < 2; ++nt) {
            const int u = 32 * w + 16 * nt + c16;
            bf16x8 bb;
            #pragma unroll
            for (int e = 0; e < 8; ++e) {
                const int v = 32 * kt + 8 * g4 + e;
                bb[e] = (__bf16)__builtin_exp2f(trans[v * Uc + u] * LOG2E);
            }
            bfr[kt][nt] = bb;
        }
    }

    {
        const int t  = tid;
        const int tg = tagb[t];
        float up = 0.f, bp = 0.f;
        if (t < L)           up = potb[(size_t)t * Uc + tg];
        if (t >= 1 && t < L) bp = trans[tagb[t - 1] * Uc + tg];
        #pragma unroll
        for (int m = 1; m < 64; m <<= 1) {
            up += __shfl_xor(up, m);
            bp += __shfl_xor(bp, m);
        }
        if (lane == 0) { redU[w] = up; redB[w] = bp; }
    }
    __syncthreads();

    const int um = 32 * w + (lane & 31);

    float pv0 = potb[(size_t)1 * Uc + um];
    float pv1 = potb[(size_t)2 * Uc + um];
    float pv2 = potb[(size_t)3 * Uc + um];
    float pv3 = potb[(size_t)4 * Uc + um];

    float er = __builtin_exp2f(potb[um] * LOG2E);
    float M;
    {
        float m = er;
        m = fmaxf(m, __shfl_xor(m, 1));
        m = fmaxf(m, __shfl_xor(m, 2));
        m = fmaxf(m, __shfl_xor(m, 4));
        m = fmaxf(m, __shfl_xor(m, 8));
        m = fmaxf(m, __shfl_xor(m, 16));
        if (lane == 0) wred[w] = m;
        __syncthreads();
        float g = fmaxf(fmaxf(fmaxf(wred[0], wred[1]), fmaxf(wred[2], wred[3])),
                        fmaxf(fmaxf(wred[4], wred[5]), fmaxf(wred[6], wred[7])));
        const float r = __builtin_amdgcn_rcpf(g);
        M  = -LN2 * __builtin_log2f(r);
        er = er * r;
        if (lane < 32) ea_lds[0][um] = (__bf16)er;
        if (lane == 0) mx[1][w] = m * r;
        __syncthreads();
    }

    #define STEPX_R(TT, PVC, RP, WP, CHK)                                      \
    {                                                                          \
        bf16x8 af[8];                                                          \
        const __bf16* ebase = &ea_lds[(RP)][8 * g4];                           \
        _Pragma("unroll")                                                      \
        for (int kt = 0; kt < 8; ++kt)                                         \
            af[kt] = *(const bf16x8*)(ebase + 32 * kt);                        \
        float pef = __builtin_exp2f((PVC) * LOG2E - CC2);                      \
        float dM = 0.0f;                                                       \
        const bool dor = (CHK) && (((TT) & 7) == 0);                           \
        if (dor) {                                                             \
            const int sl = ((TT) >> 3) & 1;                                    \
            f32x4 m0 = *(const f32x4*)&mx[sl][0];                              \
            f32x4 m1 = *(const f32x4*)&mx[sl][4];                              \
            float g = fmaxf(fmaxf(fmaxf(m0[0], m0[1]), fmaxf(m0[2], m0[3])),   \
                            fmaxf(fmaxf(m1[0], m1[1]), fmaxf(m1[2], m1[3])));  \
            const float r = __builtin_amdgcn_rcpf(g);                          \
            dM  = -LN2 * __builtin_log2f(r);                                   \
            pef *= r;                                                          \
        }                                                                      \
        const f32x4 z = {0.f, 0.f, 0.f, 0.f};                                  \
        f32x4 c0l = z, c0h = z, c1l = z, c1h = z;                              \
        _Pragma("unroll")                                                      \
        for (int kt = 0; kt < 4; ++kt) {                                       \
            c0l = __builtin_amdgcn_mfma_f32_16x16x32_bf16(af[kt], bfr[kt][0], c0l, 0, 0, 0); \
            c1l = __builtin_amdgcn_mfma_f32_16x16x32_bf16(af[kt], bfr[kt][1], c1l, 0, 0, 0); \
        }                                                                      \
        _Pragma("unroll")                                                      \
        for (int kt = 4; kt < 8; ++kt) {                                       \
            c0h = __builtin_amdgcn_mfma_f32_16x16x32_bf16(af[kt], bfr[kt][0], c0h, 0, 0, 0); \
            c1h = __builtin_amdgcn_mfma_f32_16x16x32_bf16(af[kt], bfr[kt][1], c1h, 0, 0, 0); \
        }                                                                      \
        const float s0 = c0l[0] + c0h[0];                                      \
        const float s1 = c1l[0] + c1h[0];                                      \
        const float sv = (lane & 16) ? s1 : s0;                                \
        er = sv * pef;                                                         \
        if (lane < 32) ea_lds[(WP)][um] = (__bf16)er;                          \
        if (dor) {                                                             \
            M += dM;                                                           \
            float m = er;                                                      \
            m = fmaxf(m, __shfl_xor(m, 1));                                    \
            m = fmaxf(m, __shfl_xor(m, 2));                                    \
            m = fmaxf(m, __shfl_xor(m, 4));                                    \
            m = fmaxf(m, __shfl_xor(m, 8));                                    \
            m = fmaxf(m, __shfl_xor(m, 16));                                   \
            if (lane == 0) mx[(((TT) >> 3) & 1) ^ 1][w] = m;                   \
        }                                                                      \
        wg_barrier();                                                          \
    }

    int t = 1;
    for (; t + 3 < L && t + 7 < Tc; t += 4) {
        {
            const float pvc = pv0;
            pv0 = potb[(size_t)(t + 4) * Uc + um];
            STEPX_R(t, pvc, (t + 1) & 1, t & 1, 0);
        }
        {
            const float pvc = pv1;
            pv1 = potb[(size_t)(t + 5) * Uc + um];
            STEPX_R(t + 1, pvc, t & 1, (t + 1) & 1, 0);
        }
        {
            const float pvc = pv2;
            pv2 = potb[(size_t)(t + 6) * Uc + um];
            STEPX_R(t + 2, pvc, (t + 1) & 1, t & 1, 0);
        }
        {
            const float pvc = pv3;
            pv3 = potb[(size_t)(t + 7) * Uc + um];
            STEPX_R(t + 3, pvc, t & 1, (t + 1) & 1, 1);
        }
    }
    if (t < L) { STEPX_R(t, pv0, (t + 1) & 1, t & 1, 1); ++t; }
    if (t < L) { STEPX_R(t, pv1, (t + 1) & 1, t & 1, 1); ++t; }
    if (t < L) { STEPX_R(t, pv2, (t + 1) & 1, t & 1, 1); ++t; }
    if (t < L) { STEPX_R(t, pv3, (t + 1) & 1, t & 1, 1); ++t; }
    for (; t < L; ++t) {
        const float pvc = potb[(size_t)t * Uc + um];
        STEPX_R(t, pvc, (t + 1) & 1, t & 1, 1);
    }

    {
        float ssum = er;
        ssum += __shfl_xor(ssum, 1);
        ssum += __shfl_xor(ssum, 2);
        ssum += __shfl_xor(ssum, 4);
        ssum += __shfl_xor(ssum, 8);
        ssum += __shfl_xor(ssum, 16);
        if (lane == 0) wred[w] = ssum;
        __syncthreads();
        if (tid == 0) {
            float S = 0.f, uS = 0.f, bS = 0.f;
            #pragma unroll
            for (int i = 0; i < 8; ++i) { S += wred[i]; uS += redU[i]; bS += redB[i]; }
            const float cstep = CC2 * LN2;
            const float logZ = M + (float)(L - 1) * cstep
                             + LN2 * __builtin_log2f(S);
            ws[b] = uS + bS - logZ;
            __threadfence();
            unsigned old = atomicAdd((unsigned*)(ws + Bc), 1u);
            if (old == 0xAAAAAAAAu + (unsigned)(Bc - 1)) {
                __threadfence();
                float S2 = 0.f;
                #pragma unroll
                for (int i = 0; i < Bc; ++i) S2 += ws[i];
                out[0] = -S2 * (1.0f / (float)Bc);
            }
        }
    }
    #undef STEPX_R
}

// ============================ ABLATION 1: no LDS feedback ===================
// Step code identical to production, but A-fragments read a CONSTANT third
// buffer -> the serial dependency through the LDS exchange is broken while
// instruction mix, barriers, and writes stay identical.
__global__ __launch_bounds__(512)
void abl1_nofeed(const float* __restrict__ pot, const int* __restrict__ seqlen,
                 const float* __restrict__ trans, float* __restrict__ ws,
                 size_t wssz)
{
    const int b    = blockIdx.x;
    const int tid  = threadIdx.x;
    const int lane = tid & 63;
    const int w    = tid >> 6;
    const int g4   = lane >> 4;
    const int c16  = lane & 15;
    const int L    = seqlen[b];

    __shared__ __align__(16) __bf16 ea_lds[3][Uc];
    __shared__ __align__(16) float mx[2][8];
    __shared__ float wred[8];

    const float* potb = pot + (size_t)b * Tc * Uc;

    bf16x8 bfr[8][2];
    #pragma unroll
    for (int kt = 0; kt < 8; ++kt) {
        #pragma unroll
        for (int nt = 0; nt < 2; ++nt) {
            const int u = 32 * w + 16 * nt + c16;
            bf16x8 bb;
            #pragma unroll
            for (int e = 0; e < 8; ++e) {
                const int v = 32 * kt + 8 * g4 + e;
                bb[e] = (__bf16)__builtin_exp2f(trans[v * Uc + u] * LOG2E);
            }
            bfr[kt][nt] = bb;
        }
    }

    const int um = 32 * w + (lane & 31);

    float pv0 = potb[(size_t)1 * Uc + um];
    float pv1 = potb[(size_t)2 * Uc + um];
    float pv2 = potb[(size_t)3 * Uc + um];
    float pv3 = potb[(size_t)4 * Uc + um];

    float er = __builtin_exp2f(potb[um] * LOG2E);
    float M;
    {
        float m = er;
        m = fmaxf(m, __shfl_xor(m, 1));
        m = fmaxf(m, __shfl_xor(m, 2));
        m = fmaxf(m, __shfl_xor(m, 4));
        m = fmaxf(m, __shfl_xor(m, 8));
        m = fmaxf(m, __shfl_xor(m, 16));
        if (lane == 0) wred[w] = m;
        __syncthreads();
        float g = fmaxf(fmaxf(fmaxf(wred[0], wred[1]), fmaxf(wred[2], wred[3])),
                        fmaxf(fmaxf(wred[4], wred[5]), fmaxf(wred[6], wred[7])));
        const float r = __builtin_amdgcn_rcpf(g);
        M  = -LN2 * __builtin_log2f(r);
        er = er * r;
        if (lane < 32) { ea_lds[0][um] = (__bf16)er; ea_lds[2][um] = (__bf16)er; }
        if (lane == 0) mx[1][w] = m * r;
        __syncthreads();
    }

    #define STEPX_A1(TT, PVC, RP, WP, CHK)                                     \
    {                                                                          \
        bf16x8 af[8];                                                          \
        const __bf16* ebase = &ea_lds[2][8 * g4];   /* CONSTANT buffer */      \
        _Pragma("unroll")                                                      \
        for (int kt = 0; kt < 8; ++kt)                                         \
            af[kt] = *(const bf16x8*)(ebase + 32 * kt);                        \
        float pef = __builtin_exp2f((PVC) * LOG2E - CC2);                      \
        float dM = 0.0f;                                                       \
        const bool dor = (CHK) && (((TT) & 7) == 0);                           \
        if (dor) {                                                             \
            const int sl = ((TT) >> 3) & 1;                                    \
            f32x4 m0 = *(const f32x4*)&mx[sl][0];                              \
            f32x4 m1 = *(const f32x4*)&mx[sl][4];                              \
            float g = fmaxf(fmaxf(fmaxf(m0[0], m0[1]), fmaxf(m0[2], m0[3])),   \
                            fmaxf(fmaxf(m1[0], m1[1]), fmaxf(m1[2], m1[3])));  \
            const float r = __builtin_amdgcn_rcpf(g);                          \
            dM  = -LN2 * __builtin_log2f(r);                                   \
            pef *= r;                                                          \
        }                                                                      \
        const f32x4 z = {0.f, 0.f, 0.f, 0.f};                                  \
        f32x4 c0l = z, c0h = z, c1l = z, c1h = z;                              \
        _Pragma("unroll")                                                      \
        for (int kt = 0; kt < 4; ++kt) {                                       \
            c0l = __builtin_amdgcn_mfma_f32_16x16x32_bf16(af[kt], bfr[kt][0], c0l, 0, 0, 0); \
            c1l = __builtin_amdgcn_mfma_f32_16x16x32_bf16(af[kt], bfr[kt][1], c1l, 0, 0, 0); \
        }                                                                      \
        _Pragma("unroll")                                                      \
        for (int kt = 4; kt < 8; ++kt) {                                       \
            c0h = __builtin_amdgcn_mfma_f32_16x16x32_bf16(af[kt], bfr[kt][0], c0h, 0, 0, 0); \
            c1h = __builtin_amdgcn_mfma_f32_16x16x32_bf16(af[kt], bfr[kt][1], c1h, 0, 0, 0); \
        }                                                                      \
        const float s0 = c0l[0] + c0h[0];                                      \
        const float s1 = c1l[0] + c1h[0];                                      \
        const float sv = (lane & 16) ? s1 : s0;                                \
        er = sv * pef;                                                         \
        if (lane < 32) ea_lds[(WP)][um] = (__bf16)er;                          \
        if (dor) {                                                             \
            M += dM;                                                           \
            float m = er;                                                      \
            m = fmaxf(m, __shfl_xor(m, 1));                                    \
            m = fmaxf(m, __shfl_xor(m, 2));                                    \
            m = fmaxf(m, __shfl_xor(m, 4));                                    \
            m = fmaxf(m, __shfl_xor(m, 8));                                    \
            m = fmaxf(m, __shfl_xor(m, 16));                                   \
            if (lane == 0) mx[(((TT) >> 3) & 1) ^ 1][w] = m;                   \
        }                                                                      \
        wg_barrier();                                                          \
    }

    int t = 1;
    for (; t + 3 < L && t + 7 < Tc; t += 4) {
        { const float pvc = pv0; pv0 = potb[(size_t)(t + 4) * Uc + um];
          STEPX_A1(t, pvc, (t + 1) & 1, t & 1, 0); }
        { const float pvc = pv1; pv1 = potb[(size_t)(t + 5) * Uc + um];
          STEPX_A1(t + 1, pvc, t & 1, (t + 1) & 1, 0); }
        { const float pvc = pv2; pv2 = potb[(size_t)(t + 6) * Uc + um];
          STEPX_A1(t + 2, pvc, (t + 1) & 1, t & 1, 0); }
        { const float pvc = pv3; pv3 = potb[(size_t)(t + 7) * Uc + um];
          STEPX_A1(t + 3, pvc, t & 1, (t + 1) & 1, 1); }
    }
    for (; t < L; ++t) {
        const float pvc = potb[(size_t)(t < Tc ? t : Tc - 1) * Uc + um];
        STEPX_A1(t, pvc, (t + 1) & 1, t & 1, 1);
    }
    if (lane == 0 && (size_t)((1024 + Bc * 8 + 8) * 4) <= wssz)
        ws[1024 + b * 8 + w] = er + M;
    #undef STEPX_A1
}

// ============================ ABLATION 5: no barrier ========================
// Production step code with s_barrier removed (lgkmcnt kept). Races -> data
// garbage (clamped); timing isolates the barrier/sync cost.
__global__ __launch_bounds__(512)
void abl5_nobar(const float* __restrict__ pot, const int* __restrict__ seqlen,
                const float* __restrict__ trans, float* __restrict__ ws,
                size_t wssz)
{
    const int b    = blockIdx.x;
    const int tid  = threadIdx.x;
    const int lane = tid & 63;
    const int w    = tid >> 6;
    const int g4   = lane >> 4;
    const int c16  = lane & 15;
    const int L    = seqlen[b];

    __shared__ __align__(16) __bf16 ea_lds[2][Uc];
    __shared__ float wred[8];

    const float* potb = pot + (size_t)b * Tc * Uc;

    bf16x8 bfr[8][2];
    #pragma unroll
    for (int kt = 0; kt < 8; ++kt) {
        #pragma unroll
        for (int nt = 0; nt < 2; ++nt) {
            const int u = 32 * w + 16 * nt + c16;
            bf16x8 bb;
            #pragma unroll
            for (int e = 0; e < 8; ++e) {
                const int v = 32 * kt + 8 * g4 + e;
                bb[e] = (__bf16)__builtin_exp2f(trans[v * Uc + u] * LOG2E);
            }
            bfr[kt][nt] = bb;
        }
    }

    const int um = 32 * w + (lane & 31);

    float pv0 = potb[(size_t)1 * Uc + um];
    float pv1 = potb[(size_t)2 * Uc + um];
    float pv2 = potb[(size_t)3 * Uc + um];
    float pv3 = potb[(size_t)4 * Uc + um];

    float er = __builtin_exp2f(potb[um] * LOG2E);
    {
        float m = er;
        m = fmaxf(m, __shfl_xor(m, 1));
        m = fmaxf(m, __shfl_xor(m, 2));
        m = fmaxf(m, __shfl_xor(m, 4));
        m = fmaxf(m, __shfl_xor(m, 8));
        m = fmaxf(m, __shfl_xor(m, 16));
        if (lane == 0) wred[w] = m;
        __syncthreads();
        float g = fmaxf(fmaxf(fmaxf(wred[0], wred[1]), fmaxf(wred[2], wred[3])),
                        fmaxf(fmaxf(wred[4], wred[5]), fmaxf(wred[6], wred[7])));
        er = er * __builtin_amdgcn_rcpf(g);
        if (lane < 32) ea_lds[0][um] = (__bf16)er;
        __syncthreads();
    }

    #define STEPX_A5(PVC, RP, WP)                                              \
    {                                                                          \
        bf16x8 af[8];                                                          \
        const __bf16* ebase = &ea_lds[(RP)][8 * g4];                           \
        _Pragma("unroll")                                                      \
        for (int kt = 0; kt < 8; ++kt)                                         \
            af[kt] = *(const bf16x8*)(ebase + 32 * kt);                        \
        float pef = __builtin_exp2f((PVC) * LOG2E - CC2);                      \
        const f32x4 z = {0.f, 0.f, 0.f, 0.f};                                  \
        f32x4 c0l = z, c0h = z, c1l = z, c1h = z;                              \
        _Pragma("unroll")                                                      \
        for (int kt = 0; kt < 4; ++kt) {                                       \
            c0l = __builtin_amdgcn_mfma_f32_16x16x32_bf16(af[kt], bfr[kt][0], c0l, 0, 0, 0); \
            c1l = __builtin_amdgcn_mfma_f32_16x16x32_bf16(af[kt], bfr[kt][1], c1l, 0, 0, 0); \
        }                                                                      \
        _Pragma("unroll")                                                      \
        for (int kt = 4; kt < 8; ++kt) {                                       \
            c0h = __builtin_amdgcn_mfma_f32_16x16x32_bf16(af[kt], bfr[kt][0], c0h, 0, 0, 0); \
            c1h = __builtin_amdgcn_mfma_f32_16x16x32_bf16(af[kt], bfr[kt][1], c1h, 0, 0, 0); \
        }                                                                      \
        const float s0 = c0l[0] + c0h[0];                                      \
        const float s1 = c1l[0] + c1h[0];                                      \
        const float sv = (lane & 16) ? s1 : s0;                                \
        er = fminf(fmaxf(sv * pef, 0.0f), 1e30f);                              \
        if (lane < 32) ea_lds[(WP)][um] = (__bf16)er;                          \
        lds_fence();                                                           \
    }

    int t = 1;
    for (; t + 3 < L && t + 7 < Tc; t += 4) {
        { const float pvc = pv0; pv0 = potb[(size_t)(t + 4) * Uc + um];
          STEPX_A5(pvc, (t + 1) & 1, t & 1); }
        { const float pvc = pv1; pv1 = potb[(size_t)(t + 5) * Uc + um];
          STEPX_A5(pvc, t & 1, (t + 1) & 1); }
        { const float pvc = pv2; pv2 = potb[(size_t)(t + 6) * Uc + um];
          STEPX_A5(pvc, (t + 1) & 1, t & 1); }
        { const float pvc = pv3; pv3 = potb[(size_t)(t + 7) * Uc + um];
          STEPX_A5(pvc, t & 1, (t + 1) & 1); }
    }
    for (; t < L; ++t) {
        const float pvc = potb[(size_t)(t < Tc ? t : Tc - 1) * Uc + um];
        STEPX_A5(pvc, (t + 1) & 1, t & 1);
    }
    if (lane == 0 && (size_t)((2560 + Bc * 8 + 8) * 4) <= wssz)
        ws[2560 + b * 8 + w] = er;
    #undef STEPX_A5
}

// ============================ ABLATION 3: exchange floor ====================
// Same skeleton/barrier/exchange pattern but NO MFMA: one scalar LDS read,
// trivial VALU, bf16 write. Floor cost of {ds round-trip + barrier + loop}.
__global__ __launch_bounds__(512)
void abl3_exch(const float* __restrict__ pot, const int* __restrict__ seqlen,
               float* __restrict__ ws, size_t wssz)
{
    const int b    = blockIdx.x;
    const int tid  = threadIdx.x;
    const int lane = tid & 63;
    const int w    = tid >> 6;
    const int L    = seqlen[b];

    __shared__ __align__(16) __bf16 ea_lds[2][Uc];

    const float* potb = pot + (size_t)b * Tc * Uc;
    const int um = 32 * w + (lane & 31);

    float pv0 = potb[(size_t)1 * Uc + um];
    float pv1 = potb[(size_t)2 * Uc + um];
    float pv2 = potb[(size_t)3 * Uc + um];
    float pv3 = potb[(size_t)4 * Uc + um];

    float er = __builtin_exp2f(potb[um] * LOG2E);
    if (lane < 32) ea_lds[0][um] = (__bf16)er;
    __syncthreads();

    #define STEP3(PVC, RP, WP)                                                 \
    {                                                                          \
        const float x = (float)ea_lds[(RP)][(um + 7) & 255];                   \
        const float pef = __builtin_exp2f((PVC) * LOG2E - CC2);                \
        er = fminf(x * pef + er * 0.5f, 1e30f);                                \
        if (lane < 32) ea_lds[(WP)][um] = (__bf16)er;                          \
        wg_barrier();                                                          \
    }

    int t = 1;
    for (; t + 3 < L && t + 7 < Tc; t += 4) {
        { const float pvc = pv0; pv0 = potb[(size_t)(t + 4) * Uc + um];
          STEP3(pvc, (t + 1) & 1, t & 1); }
        { const float pvc = pv1; pv1 = potb[(size_t)(t + 5) * Uc + um];
          STEP3(pvc, t & 1, (t + 1) & 1); }
        { const float pvc = pv2; pv2 = potb[(size_t)(t + 6) * Uc + um];
          STEP3(pvc, (t + 1) & 1, t & 1); }
        { const float pvc = pv3; pv3 = potb[(size_t)(t + 7) * Uc + um];
          STEP3(pvc, t & 1, (t + 1) & 1); }
    }
    for (; t < L; ++t) {
        const float pvc = potb[(size_t)(t < Tc ? t : Tc - 1) * Uc + um];
        STEP3(pvc, (t + 1) & 1, t & 1);
    }
    if (lane == 0 && (size_t)((1536 + Bc * 8 + 8) * 4) <= wssz)
        ws[1536 + b * 8 + w] = er;
    #undef STEP3
}

// ============================ ABLATION 4: compute floor =====================
// Same skeleton but NO LDS and NO barrier: MFMA chain fed from registers
// with a real serial dependency (er -> af -> MFMA -> er).
__global__ __launch_bounds__(512)
void abl4_comp(const float* __restrict__ pot, const int* __restrict__ seqlen,
               const float* __restrict__ trans, float* __restrict__ ws,
               size_t wssz)
{
    const int b    = blockIdx.x;
    const int tid  = threadIdx.x;
    const int lane = tid & 63;
    const int w    = tid >> 6;
    const int g4   = lane >> 4;
    const int c16  = lane & 15;
    const int L    = seqlen[b];

    const float* potb = pot + (size_t)b * Tc * Uc;

    bf16x8 bfr[8][2];
    #pragma unroll
    for (int kt = 0; kt < 8; ++kt) {
        #pragma unroll
        for (int nt = 0; nt < 2; ++nt) {
            const int u = 32 * w + 16 * nt + c16;
            bf16x8 bb;
            #pragma unroll
            for (int e = 0; e < 8; ++e) {
                const int v = 32 * kt + 8 * g4 + e;
                bb[e] = (__bf16)__builtin_exp2f(trans[v * Uc + u] * LOG2E);
            }
            bfr[kt][nt] = bb;
        }
    }

    const int um = 32 * w + (lane & 31);

    float pv0 = potb[(size_t)1 * Uc + um];
    float pv1 = potb[(size_t)2 * Uc + um];
    float pv2 = potb[(size_t)3 * Uc + um];
    float pv3 = potb[(size_t)4 * Uc + um];

    float er = __builtin_exp2f(potb[um] * LOG2E);

    #define STEP4(PVC)                                                         \
    {                                                                          \
        const float pef = __builtin_exp2f((PVC) * LOG2E - CC2);                \
        const __bf16 v16 = (__bf16)er;                                         \
        bf16x8 a0 = {v16, v16, v16, v16, v16, v16, v16, v16};                  \
        const f32x4 z = {0.f, 0.f, 0.f, 0.f};                                  \
        f32x4 c0l = z, c0h = z, c1l = z, c1h = z;                              \
        _Pragma("unroll")                                                      \
        for (int kt = 0; kt < 4; ++kt) {                                       \
            c0l = __builtin_amdgcn_mfma_f32_16x16x32_bf16(a0, bfr[kt][0], c0l, 0, 0, 0); \
            c1l = __builtin_amdgcn_mfma_f32_16x16x32_bf16(a0, bfr[kt][1], c1l, 0, 0, 0); \
        }                                                                      \
        _Pragma("unroll")                                                      \
        for (int kt = 4; kt < 8; ++kt) {                                       \
            c0h = __builtin_amdgcn_mfma_f32_16x16x32_bf16(a0, bfr[kt][0], c0h, 0, 0, 0); \
            c1h = __builtin_amdgcn_mfma_f32_16x16x32_bf16(a0, bfr[kt][1], c1h, 0, 0, 0); \
        }                                                                      \
        const float s0 = c0l[0] + c0h[0];                                      \
        const float s1 = c1l[0] + c1h[0];                                      \
        const float sv = (lane & 16) ? s1 : s0;                                \
        er = fminf(sv * pef, 1e30f);                                           \
    }

    int t = 1;
    for (; t + 3 < L && t + 7 < Tc; t += 4) {
        { const float pvc = pv0; pv0 = potb[(size_t)(t + 4) * Uc + um]; STEP4(pvc); }
        { const float pvc = pv1; pv1 = potb[(size_t)(t + 5) * Uc + um]; STEP4(pvc); }
        { const float pvc = pv2; pv2 = potb[(size_t)(t + 6) * Uc + um]; STEP4(pvc); }
        { const float pvc = pv3; pv3 = potb[(size_t)(t + 7) * Uc + um]; STEP4(pvc); }
    }
    for (; t < L; ++t) {
        const float pvc = potb[(size_t)(t < Tc ? t : Tc - 1) * Uc + um];
        STEP4(pvc);
    }
    if (lane == 0 && (size_t)((2048 + Bc * 8 + 8) * 4) <= wssz)
        ws[2048 + b * 8 + w] = er;
    #undef STEP4
}

extern "C" void kernel_launch(void* const* d_in, const int* in_sizes, int n_in,
                              void* d_out, int out_size, void* d_ws, size_t ws_size,
                              hipStream_t stream) {
    const float* pot   = (const float*)d_in[0];
    const int*   tags  = (const int*)d_in[1];
    const int*   slen  = (const int*)d_in[2];
    const float* trans = (const float*)d_in[3];
    float* wsf = (float*)d_ws;
    float* out = (float*)d_out;

    crf_fwd<<<Bc, 512, 0, stream>>>(pot, tags, slen, trans, wsf, out);
    abl1_nofeed<<<Bc, 512, 0, stream>>>(pot, slen, trans, wsf, ws_size);
    abl5_nobar<<<Bc, 512, 0, stream>>>(pot, slen, trans, wsf, ws_size);
    abl3_exch<<<Bc, 512, 0, stream>>>(pot, slen, wsf, ws_size);
    abl4_comp<<<Bc, 512, 0, stream>>>(pot, slen, trans, wsf, ws_size);
}